// Round 6
// baseline (223.510 us; speedup 1.0000x reference)
//
#include <hip/hip_runtime.h>
#include <cstdint>
#include <cstddef>

#define BB 2
#define CC 256
#define NN 16
#define LL 4096
#define NCH 128
#define CLEN 32
#define LCH 8           // l-chunk per k1 block
#define LOG2E 1.4426950408889634f

__device__ __forceinline__ float softplus_f(float z) {
    return fmaxf(z, 0.f) + log1pf(expf(-fabsf(z)));
}

// ---------------- K1: delta/u + Bm/Cm in one LDS-free, barrier-free sweep ---
// thread = c (256), block = (b, l-chunk of 8). 1024 blocks -> 4 blocks/CU,
// 16 waves/CU (R5 had 2 blocks/CU = latency-bound at Occ 18%).
__global__ __launch_bounds__(256) void k1_delta_gemm(
    const float* __restrict__ feat, const float* __restrict__ Wd,
    const float* __restrict__ bd, const float* __restrict__ WB,
    const float* __restrict__ WC, float* __restrict__ du,
    float* __restrict__ Bm, float* __restrict__ Cm)
{
    int lc = blockIdx.x & 511;          // 512 l-chunks of 8
    int b  = blockIdx.x >> 9;
    int l0 = lc * LCH;
    int c  = threadIdx.x;
    const float* fbase = feat + (size_t)b * CC * LL;

    // Bm/Cm mapping: 32 threads per l; mat = bit4, n = low 4 bits
    int lB  = threadIdx.x >> 5;         // 0..7
    int s   = threadIdx.x & 31;
    int mat = s >> 4;                   // 0=Bm 1=Cm
    int n   = s & 15;
    const float* wBC = mat ? WC : WB;

    float accM[LCH] = {};
    float accB = 0.f;

    #pragma unroll 4
    for (int k = 0; k < 256; ++k) {
        const float* frow = fbase + (size_t)k * LL + l0;
        // wave-uniform feat chunk (8 floats) -> scalar loads
        float4 x0 = *(const float4*)(frow + 0);
        float4 x1 = *(const float4*)(frow + 4);
        // per-thread W column element (coalesced, L2-resident)
        float wv = Wd[(size_t)k * CC + c];
        // BC operands
        float wb = wBC[k * NN + n];
        float xb = frow[lB];            // 2 distinct addrs/wave -> broadcast

        accM[0] = fmaf(x0.x, wv, accM[0]);
        accM[1] = fmaf(x0.y, wv, accM[1]);
        accM[2] = fmaf(x0.z, wv, accM[2]);
        accM[3] = fmaf(x0.w, wv, accM[3]);
        accM[4] = fmaf(x1.x, wv, accM[4]);
        accM[5] = fmaf(x1.y, wv, accM[5]);
        accM[6] = fmaf(x1.z, wv, accM[6]);
        accM[7] = fmaf(x1.w, wv, accM[7]);
        accB = fmaf(xb, wb, accB);
    }

    // Bm/Cm store (each (l,mat,n) computed exactly once)
    (mat ? Cm : Bm)[((size_t)b * LL + l0 + lB) * NN + n] = accB;

    // epilogue: delta = softplus(acc + bd), u = delta * x
    float bdc = bd[c];
    float4 fx[2];
    {
        const float* fcp = fbase + (size_t)c * LL + l0;
        fx[0] = *(const float4*)(fcp + 0);
        fx[1] = *(const float4*)(fcp + 4);
    }
    float2* du2 = (float2*)du;
    const float* fxs = (const float*)fx;
    #pragma unroll
    for (int j = 0; j < LCH; ++j) {
        float dv = softplus_f(accM[j] + bdc);
        float uv = dv * fxs[j];
        du2[((size_t)b * LL + l0 + j) * CC + c] = make_float2(dv, uv);
    }
}

// ---------------- P1: per-chunk aggregates, n-split (512 thr, 24 waves/CU) --
__global__ __launch_bounds__(512) void p1_aggr(
    const float2* __restrict__ du, const float* __restrict__ Bm,
    const float* __restrict__ A_log, float* __restrict__ P, float* __restrict__ S)
{
    int blk = blockIdx.x;
    int cls = blk >> 8;
    int b   = (blk >> 7) & 1;
    int ch  = blk & 127;
    int p0, inner;
    if (cls == 0)      { p0 = 32 * ch;        inner = 1; }
    else if (cls == 1) { p0 = 4095 - 32 * ch; inner = -1; }
    else               { p0 = 63 - (ch >> 1) + 2048 * (ch & 1); inner = 64; }
    int c  = threadIdx.x & 255;
    int nh = threadIdx.x >> 8;          // n-half
    int n0 = nh * 8;
    __shared__ float sBm[CLEN * NN];
    for (int i = threadIdx.x; i < CLEN * NN; i += 512) {
        int j = i >> 4, nn = i & 15;
        sBm[i] = Bm[((size_t)b * LL + (p0 + inner * j)) * NN + nn];
    }
    float A2[8];
    {
        const float4* al = (const float4*)(A_log + c * NN + n0);
        float4 v0 = al[0], v1 = al[1];
        A2[0] = -expf(v0.x) * LOG2E; A2[1] = -expf(v0.y) * LOG2E;
        A2[2] = -expf(v0.z) * LOG2E; A2[3] = -expf(v0.w) * LOG2E;
        A2[4] = -expf(v1.x) * LOG2E; A2[5] = -expf(v1.y) * LOG2E;
        A2[6] = -expf(v1.z) * LOG2E; A2[7] = -expf(v1.w) * LOG2E;
    }
    __syncthreads();
    float Sv[8] = {};
    float sumd = 0.f;
    const float2* dub = du + (size_t)b * LL * CC + c;
    for (int j = 0; j < CLEN; ++j) {
        float2 dv = dub[(size_t)(p0 + inner * j) * CC];
        sumd += dv.x;
        float dA[8];
        #pragma unroll
        for (int i = 0; i < 8; ++i) dA[i] = __builtin_amdgcn_exp2f(A2[i] * dv.x);
        #pragma unroll
        for (int i = 0; i < 8; ++i)
            Sv[i] = fmaf(dA[i], Sv[i], dv.y * sBm[j * 16 + n0 + i]);
    }
    size_t base = ((size_t)((cls * 2 + b) * 128 + ch)) * 4096 + (size_t)c * 16 + n0;
    #pragma unroll
    for (int i = 0; i < 8; ++i) {
        P[base + i] = __builtin_amdgcn_exp2f(A2[i] * sumd);
        S[base + i] = Sv[i];
    }
}

// ---------------- P2: scan chunk aggregates per direction -> Hin ------------
__global__ __launch_bounds__(128) void p2_scan(
    const float* __restrict__ P, const float* __restrict__ S, float* __restrict__ Hin)
{
    int r = blockIdx.x * 128 + threadIdx.x;   // 32768 rows
    int cn = r & 4095;
    int db = r >> 12;
    int d = db >> 1;
    int cls = (d == 1) ? 1 : ((d == 3) ? 2 : 0);
    int b = db & 1;
    const size_t cbase = ((size_t)(cls * 2 + b) * 128) * 4096 + cn;
    const size_t obase = ((size_t)db * 128) * 4096 + cn;
    float h = 0.f;
    for (int g = 0; g < 16; ++g) {
        float pv[8], sv[8];
        #pragma unroll
        for (int i = 0; i < 8; ++i) {
            int ch = g * 8 + i;
            int chm = (d == 2) ? (126 - 2 * (ch >> 1) + (ch & 1)) : ch;
            size_t ix = cbase + (size_t)chm * 4096;
            pv[i] = P[ix];
            sv[i] = S[ix];
        }
        #pragma unroll
        for (int i = 0; i < 8; ++i) {
            Hin[obase + (size_t)(g * 8 + i) * 4096] = h;
            h = fmaf(pv[i], h, sv[i]);
        }
    }
}

// ---------------- P3: replay, n-split 512 thr; y accumulated in LDS via
// ds_add (no per-step barrier), bulk-written at chunk end. -------------------
__global__ __launch_bounds__(512) void p3_replay(
    const float2* __restrict__ du, const float* __restrict__ Bm,
    const float* __restrict__ Cm, const float* __restrict__ A_log,
    const float* __restrict__ Hin, float* __restrict__ yA,
    float* __restrict__ yB, float* __restrict__ yC)
{
    int blk = blockIdx.x;
    int sec = blk >> 8;
    int b   = (blk >> 7) & 1;
    int ch  = blk & 127;
    int p0, inner;
    if (sec == 0)      { p0 = 32 * ch;        inner = 1; }
    else if (sec == 1) { p0 = 4095 - 32 * ch; inner = -1; }
    else               { p0 = 63 - (ch >> 1) + 2048 * (ch & 1); inner = 64; }
    int c  = threadIdx.x & 255;
    int nh = threadIdx.x >> 8;
    int n0 = nh * 8;
    __shared__ float sBm[CLEN * NN];
    __shared__ float sCm[CLEN * NN];
    __shared__ float sY[CLEN * CC];     // 32 KB
    for (int i = threadIdx.x; i < CLEN * NN; i += 512) {
        int j = i >> 4, nn = i & 15;
        size_t o = ((size_t)b * LL + (p0 + inner * j)) * NN + nn;
        sBm[i] = Bm[o];
        sCm[i] = Cm[o];
    }
    for (int i = threadIdx.x; i < CLEN * CC; i += 512) sY[i] = 0.f;
    float A2[8];
    {
        const float4* al = (const float4*)(A_log + c * NN + n0);
        float4 v0 = al[0], v1 = al[1];
        A2[0] = -expf(v0.x) * LOG2E; A2[1] = -expf(v0.y) * LOG2E;
        A2[2] = -expf(v0.z) * LOG2E; A2[3] = -expf(v0.w) * LOG2E;
        A2[4] = -expf(v1.x) * LOG2E; A2[5] = -expf(v1.y) * LOG2E;
        A2[6] = -expf(v1.z) * LOG2E; A2[7] = -expf(v1.w) * LOG2E;
    }
    const float2* dub = du + (size_t)b * LL * CC + c;

    if (sec == 0) {
        int ch2 = 126 - (ch & ~1) + (ch & 1);
        float h0[8], h2[8];
        {
            const float4* hp0 = (const float4*)(Hin + ((size_t)(0 * 2 + b) * 128 + ch)  * 4096 + (size_t)c * 16 + n0);
            const float4* hp2 = (const float4*)(Hin + ((size_t)(2 * 2 + b) * 128 + ch2) * 4096 + (size_t)c * 16 + n0);
            float4 v0 = hp0[0], v1 = hp0[1], w0 = hp2[0], w1 = hp2[1];
            h0[0]=v0.x; h0[1]=v0.y; h0[2]=v0.z; h0[3]=v0.w;
            h0[4]=v1.x; h0[5]=v1.y; h0[6]=v1.z; h0[7]=v1.w;
            h2[0]=w0.x; h2[1]=w0.y; h2[2]=w0.z; h2[3]=w0.w;
            h2[4]=w1.x; h2[5]=w1.y; h2[6]=w1.z; h2[7]=w1.w;
        }
        __syncthreads();
        for (int j = 0; j < CLEN; ++j) {
            float2 dv = dub[(size_t)(p0 + j) * CC];
            float dA[8];
            #pragma unroll
            for (int i = 0; i < 8; ++i) dA[i] = __builtin_amdgcn_exp2f(A2[i] * dv.x);
            float part = 0.f;
            #pragma unroll
            for (int i = 0; i < 8; ++i) {
                float Bu = dv.y * sBm[j * 16 + n0 + i];
                float cm = sCm[j * 16 + n0 + i];
                h0[i] = fmaf(dA[i], h0[i], Bu);
                h2[i] = fmaf(dA[i], h2[i], Bu);
                part = fmaf(h0[i] + h2[i], cm, part);
            }
            atomicAdd(&sY[j * CC + c], 0.25f * part);
        }
    } else {
        int d = (sec == 1) ? 1 : 3;
        float h[8];
        {
            const float4* hp = (const float4*)(Hin + ((size_t)(d * 2 + b) * 128 + ch) * 4096 + (size_t)c * 16 + n0);
            float4 v0 = hp[0], v1 = hp[1];
            h[0]=v0.x; h[1]=v0.y; h[2]=v0.z; h[3]=v0.w;
            h[4]=v1.x; h[5]=v1.y; h[6]=v1.z; h[7]=v1.w;
        }
        __syncthreads();
        for (int j = 0; j < CLEN; ++j) {
            float2 dv = dub[(size_t)(p0 + inner * j) * CC];
            float dA[8];
            #pragma unroll
            for (int i = 0; i < 8; ++i) dA[i] = __builtin_amdgcn_exp2f(A2[i] * dv.x);
            float part = 0.f;
            #pragma unroll
            for (int i = 0; i < 8; ++i) {
                float Bu = dv.y * sBm[j * 16 + n0 + i];
                h[i] = fmaf(dA[i], h[i], Bu);
                part = fmaf(h[i], sCm[j * 16 + n0 + i], part);
            }
            atomicAdd(&sY[j * CC + c], 0.25f * part);
        }
    }
    __syncthreads();
    // bulk write: 32 token-rows of 256 floats
    float* yD = (sec == 0) ? yA : ((sec == 1) ? yB : yC);
    int r   = threadIdx.x >> 4;          // 0..31 global row
    int cg  = (threadIdx.x & 15) * 16;   // 16 floats per thread
    int jj  = (sec == 1) ? (31 - r) : r; // LDS row for this global row
    int tok = (sec == 2) ? (p0 + 64 * r) : ((sec == 1) ? (p0 - 31 + r) : (p0 + r));
    float* gp = yD + ((size_t)b * LL + tok) * CC + cg;
    const float* lp = &sY[jj * CC + cg];
    #pragma unroll
    for (int q = 0; q < 4; ++q)
        *(float4*)(gp + q * 4) = *(const float4*)(lp + q * 4);
}

// ---------------- K6: sum 3 y-buffers + x*D, transpose to (B,C,L) -----------
__global__ __launch_bounds__(256) void k6_reduce(
    const float* __restrict__ feat, const float* __restrict__ D,
    const float* __restrict__ yA, const float* __restrict__ yB,
    const float* __restrict__ yC, float* __restrict__ out)
{
    int pt = blockIdx.x & 63;
    int ct = (blockIdx.x >> 6) & 3;
    int b  = blockIdx.x >> 8;
    int p0 = pt * 64, c0 = ct * 64;
    __shared__ float tile[64 * 65];
    {
        int cl = threadIdx.x & 63;
        int pg = threadIdx.x >> 6;
        #pragma unroll
        for (int pp = 0; pp < 16; ++pp) {
            int pl = pp * 4 + pg;
            size_t ix = ((size_t)b * LL + p0 + pl) * CC + c0 + cl;
            tile[cl * 65 + pl] = yA[ix] + yB[ix] + yC[ix];
        }
    }
    __syncthreads();
    {
        int pl = threadIdx.x & 63;
        int cg = threadIdx.x >> 6;
        #pragma unroll
        for (int cc = 0; cc < 16; ++cc) {
            int cloc = cc * 4 + cg;
            int c = c0 + cloc;
            size_t o = ((size_t)b * CC + c) * LL + p0 + pl;
            out[o] = tile[cloc * 65 + pl] + feat[o] * D[c];
        }
    }
}

extern "C" void kernel_launch(void* const* d_in, const int* in_sizes, int n_in,
                              void* d_out, int out_size, void* d_ws, size_t ws_size,
                              hipStream_t stream)
{
    const float* feat  = (const float*)d_in[0];
    const float* A_log = (const float*)d_in[1];
    const float* D     = (const float*)d_in[2];
    const float* Wd    = (const float*)d_in[3];
    const float* bd    = (const float*)d_in[4];
    const float* WB    = (const float*)d_in[5];
    const float* WC    = (const float*)d_in[6];
    float* out = (float*)d_out;

    float* ws  = (float*)d_ws;
    float* du  = ws;                                      //  4,194,304 (float2 pairs)
    float* Bm  = du  + (size_t)4194304;                   //    131,072
    float* Cm  = Bm  + (size_t)131072;                    //    131,072
    float* P   = Cm  + (size_t)131072;                    //  3,145,728 (3 cls)
    float* S   = P   + (size_t)3145728;                   //  3,145,728
    float* Hin = S   + (size_t)3145728;                   //  4,194,304 (4 dirs)
    float* yA  = Hin + (size_t)4194304;                   //  2,097,152
    float* yB  = yA  + (size_t)2097152;                   //  2,097,152
    float* yC  = yB  + (size_t)2097152;                   //  2,097,152

    k1_delta_gemm<<<1024, 256, 0, stream>>>(feat, Wd, bd, WB, WC, du, Bm, Cm);
    p1_aggr<<<768, 512, 0, stream>>>((const float2*)du, Bm, A_log, P, S);
    p2_scan<<<256, 128, 0, stream>>>(P, S, Hin);
    p3_replay<<<768, 512, 0, stream>>>((const float2*)du, Bm, Cm, A_log, Hin, yA, yB, yC);
    k6_reduce<<<512, 256, 0, stream>>>(feat, D, yA, yB, yC, out);
}

// Round 7
// 172.852 us; speedup vs baseline: 1.2931x; 1.2931x over previous
//
#include <hip/hip_runtime.h>
#include <cstdint>
#include <cstddef>

#define BB 2
#define CC 256
#define NN 16
#define LL 4096
#define NCH 128
#define CLEN 32
#define LCH 8           // l-chunk per k1 block
#define LOG2E 1.4426950408889634f

__device__ __forceinline__ float softplus_f(float z) {
    return fmaxf(z, 0.f) + log1pf(expf(-fabsf(z)));
}

// ---------------- K1: delta/u + Bm/Cm in one LDS-free, barrier-free sweep ---
// thread = c (256), block = (b, l-chunk of 8). 1024 blocks -> 4 blocks/CU.
__global__ __launch_bounds__(256) void k1_delta_gemm(
    const float* __restrict__ feat, const float* __restrict__ Wd,
    const float* __restrict__ bd, const float* __restrict__ WB,
    const float* __restrict__ WC, float* __restrict__ du,
    float* __restrict__ Bm, float* __restrict__ Cm)
{
    int lc = blockIdx.x & 511;          // 512 l-chunks of 8
    int b  = blockIdx.x >> 9;
    int l0 = lc * LCH;
    int c  = threadIdx.x;
    const float* fbase = feat + (size_t)b * CC * LL;

    // Bm/Cm mapping: 32 threads per l; mat = bit4, n = low 4 bits
    int lB  = threadIdx.x >> 5;         // 0..7
    int s   = threadIdx.x & 31;
    int mat = s >> 4;                   // 0=Bm 1=Cm
    int n   = s & 15;
    const float* wBC = mat ? WC : WB;

    float accM[LCH] = {};
    float accB = 0.f;

    #pragma unroll 4
    for (int k = 0; k < 256; ++k) {
        const float* frow = fbase + (size_t)k * LL + l0;
        float4 x0 = *(const float4*)(frow + 0);
        float4 x1 = *(const float4*)(frow + 4);
        float wv = Wd[(size_t)k * CC + c];
        float wb = wBC[k * NN + n];
        float xb = frow[lB];

        accM[0] = fmaf(x0.x, wv, accM[0]);
        accM[1] = fmaf(x0.y, wv, accM[1]);
        accM[2] = fmaf(x0.z, wv, accM[2]);
        accM[3] = fmaf(x0.w, wv, accM[3]);
        accM[4] = fmaf(x1.x, wv, accM[4]);
        accM[5] = fmaf(x1.y, wv, accM[5]);
        accM[6] = fmaf(x1.z, wv, accM[6]);
        accM[7] = fmaf(x1.w, wv, accM[7]);
        accB = fmaf(xb, wb, accB);
    }

    (mat ? Cm : Bm)[((size_t)b * LL + l0 + lB) * NN + n] = accB;

    float bdc = bd[c];
    float4 fx[2];
    {
        const float* fcp = fbase + (size_t)c * LL + l0;
        fx[0] = *(const float4*)(fcp + 0);
        fx[1] = *(const float4*)(fcp + 4);
    }
    float2* du2 = (float2*)du;
    const float* fxs = (const float*)fx;
    #pragma unroll
    for (int j = 0; j < LCH; ++j) {
        float dv = softplus_f(accM[j] + bdc);
        float uv = dv * fxs[j];
        du2[((size_t)b * LL + l0 + j) * CC + c] = make_float2(dv, uv);
    }
}

// ---------------- P1: per-chunk aggregates, 2-deep x 8-wide du prefetch -----
__global__ __launch_bounds__(256) void p1_aggr(
    const float2* __restrict__ du, const float* __restrict__ Bm,
    const float* __restrict__ A_log, float* __restrict__ P, float* __restrict__ S)
{
    int blk = blockIdx.x;
    int cls = blk >> 8;
    int b   = (blk >> 7) & 1;
    int ch  = blk & 127;
    int p0, inner;
    if (cls == 0)      { p0 = 32 * ch;        inner = 1; }
    else if (cls == 1) { p0 = 4095 - 32 * ch; inner = -1; }
    else               { p0 = 63 - (ch >> 1) + 2048 * (ch & 1); inner = 64; }
    int c = threadIdx.x;
    __shared__ float sBm[CLEN * NN];
    for (int i = threadIdx.x; i < CLEN * NN; i += 256) {
        int j = i >> 4, nn = i & 15;
        sBm[i] = Bm[((size_t)b * LL + (p0 + inner * j)) * NN + nn];
    }
    float A2[NN];
    {
        const float4* al = (const float4*)(A_log + c * NN);
        #pragma unroll
        for (int q = 0; q < 4; ++q) {
            float4 v = al[q];
            A2[q*4+0] = -expf(v.x) * LOG2E;
            A2[q*4+1] = -expf(v.y) * LOG2E;
            A2[q*4+2] = -expf(v.z) * LOG2E;
            A2[q*4+3] = -expf(v.w) * LOG2E;
        }
    }
    __syncthreads();
    const float2* dub = du + (size_t)b * LL * CC + c;
    float2 buf[2][8];
    #pragma unroll
    for (int i = 0; i < 8; ++i)
        buf[0][i] = dub[(size_t)(p0 + inner * i) * CC];
    float Sv[NN] = {};
    float sumd = 0.f;
    #pragma unroll
    for (int g = 0; g < 4; ++g) {
        if (g < 3) {
            #pragma unroll
            for (int i = 0; i < 8; ++i)
                buf[(g + 1) & 1][i] = dub[(size_t)(p0 + inner * ((g + 1) * 8 + i)) * CC];
        }
        #pragma unroll
        for (int i = 0; i < 8; ++i) {
            int j = g * 8 + i;
            float2 dv = buf[g & 1][i];
            sumd += dv.x;
            float dA[NN];
            #pragma unroll
            for (int nn = 0; nn < NN; ++nn) dA[nn] = __builtin_amdgcn_exp2f(A2[nn] * dv.x);
            #pragma unroll
            for (int nn = 0; nn < NN; ++nn)
                Sv[nn] = fmaf(dA[nn], Sv[nn], dv.y * sBm[j * 16 + nn]);
        }
    }
    size_t base = ((size_t)((cls * 2 + b) * 128 + ch)) * 4096 + (size_t)c * 16;
    #pragma unroll
    for (int nn = 0; nn < NN; ++nn) {
        P[base + nn] = __builtin_amdgcn_exp2f(A2[nn] * sumd);
        S[base + nn] = Sv[nn];
    }
}

// ---------------- P2: scan chunk aggregates per direction -> Hin ------------
__global__ __launch_bounds__(128) void p2_scan(
    const float* __restrict__ P, const float* __restrict__ S, float* __restrict__ Hin)
{
    int r = blockIdx.x * 128 + threadIdx.x;   // 32768 rows
    int cn = r & 4095;
    int db = r >> 12;
    int d = db >> 1;
    int cls = (d == 1) ? 1 : ((d == 3) ? 2 : 0);
    int b = db & 1;
    const size_t cbase = ((size_t)(cls * 2 + b) * 128) * 4096 + cn;
    const size_t obase = ((size_t)db * 128) * 4096 + cn;
    float h = 0.f;
    for (int g = 0; g < 16; ++g) {
        float pv[8], sv[8];
        #pragma unroll
        for (int i = 0; i < 8; ++i) {
            int ch = g * 8 + i;
            int chm = (d == 2) ? (126 - 2 * (ch >> 1) + (ch & 1)) : ch;
            size_t ix = cbase + (size_t)chm * 4096;
            pv[i] = P[ix];
            sv[i] = S[ix];
        }
        #pragma unroll
        for (int i = 0; i < 8; ++i) {
            Hin[obase + (size_t)(g * 8 + i) * 4096] = h;
            h = fmaf(pv[i], h, sv[i]);
        }
    }
}

// ---------------- P3: replay, R5 structure + 2-deep x 8-wide du prefetch ----
__global__ __launch_bounds__(256) void p3_replay(
    const float2* __restrict__ du, const float* __restrict__ Bm,
    const float* __restrict__ Cm, const float* __restrict__ A_log,
    const float* __restrict__ Hin, float* __restrict__ yA,
    float* __restrict__ yB, float* __restrict__ yC)
{
    int blk = blockIdx.x;
    int sec = blk >> 8;
    int b   = (blk >> 7) & 1;
    int ch  = blk & 127;
    int p0, inner;
    if (sec == 0)      { p0 = 32 * ch;        inner = 1; }
    else if (sec == 1) { p0 = 4095 - 32 * ch; inner = -1; }
    else               { p0 = 63 - (ch >> 1) + 2048 * (ch & 1); inner = 64; }
    int c = threadIdx.x;
    __shared__ float sBm[CLEN * NN];
    __shared__ float sCm[CLEN * NN];
    for (int i = threadIdx.x; i < CLEN * NN; i += 256) {
        int j = i >> 4, nn = i & 15;
        size_t o = ((size_t)b * LL + (p0 + inner * j)) * NN + nn;
        sBm[i] = Bm[o];
        sCm[i] = Cm[o];
    }
    float A2[NN];
    {
        const float4* al = (const float4*)(A_log + c * NN);
        #pragma unroll
        for (int q = 0; q < 4; ++q) {
            float4 v = al[q];
            A2[q*4+0] = -expf(v.x) * LOG2E;
            A2[q*4+1] = -expf(v.y) * LOG2E;
            A2[q*4+2] = -expf(v.z) * LOG2E;
            A2[q*4+3] = -expf(v.w) * LOG2E;
        }
    }
    const float2* dub = du + (size_t)b * LL * CC + c;

    if (sec == 0) {
        int ch2 = 126 - (ch & ~1) + (ch & 1);
        float h0[NN], h2[NN];
        {
            const float4* hp0 = (const float4*)(Hin + ((size_t)(0 * 2 + b) * 128 + ch)  * 4096 + (size_t)c * 16);
            const float4* hp2 = (const float4*)(Hin + ((size_t)(2 * 2 + b) * 128 + ch2) * 4096 + (size_t)c * 16);
            #pragma unroll
            for (int q = 0; q < 4; ++q) {
                float4 v0 = hp0[q], v2 = hp2[q];
                h0[q*4+0]=v0.x; h0[q*4+1]=v0.y; h0[q*4+2]=v0.z; h0[q*4+3]=v0.w;
                h2[q*4+0]=v2.x; h2[q*4+1]=v2.y; h2[q*4+2]=v2.z; h2[q*4+3]=v2.w;
            }
        }
        __syncthreads();
        float2 buf[2][8];
        #pragma unroll
        for (int i = 0; i < 8; ++i)
            buf[0][i] = dub[(size_t)(p0 + i) * CC];
        #pragma unroll
        for (int g = 0; g < 4; ++g) {
            if (g < 3) {
                #pragma unroll
                for (int i = 0; i < 8; ++i)
                    buf[(g + 1) & 1][i] = dub[(size_t)(p0 + (g + 1) * 8 + i) * CC];
            }
            #pragma unroll
            for (int i = 0; i < 8; ++i) {
                int j = g * 8 + i;
                float2 dv = buf[g & 1][i];
                float dA[NN];
                #pragma unroll
                for (int nn = 0; nn < NN; ++nn) dA[nn] = __builtin_amdgcn_exp2f(A2[nn] * dv.x);
                float y0v = 0.f, y2v = 0.f;
                #pragma unroll
                for (int nn = 0; nn < NN; ++nn) {
                    float Bu = dv.y * sBm[j * 16 + nn];
                    float cm = sCm[j * 16 + nn];
                    h0[nn] = fmaf(dA[nn], h0[nn], Bu);
                    h2[nn] = fmaf(dA[nn], h2[nn], Bu);
                    y0v = fmaf(h0[nn], cm, y0v);
                    y2v = fmaf(h2[nn], cm, y2v);
                }
                yA[((size_t)b * LL + p0 + j) * CC + c] = 0.25f * (y0v + y2v);
            }
        }
    } else {
        int d = (sec == 1) ? 1 : 3;
        float h[NN];
        {
            const float4* hp = (const float4*)(Hin + ((size_t)(d * 2 + b) * 128 + ch) * 4096 + (size_t)c * 16);
            #pragma unroll
            for (int q = 0; q < 4; ++q) {
                float4 v = hp[q];
                h[q*4+0]=v.x; h[q*4+1]=v.y; h[q*4+2]=v.z; h[q*4+3]=v.w;
            }
        }
        __syncthreads();
        float* yD = (sec == 1) ? yB : yC;
        float2 buf[2][8];
        #pragma unroll
        for (int i = 0; i < 8; ++i)
            buf[0][i] = dub[(size_t)(p0 + inner * i) * CC];
        #pragma unroll
        for (int g = 0; g < 4; ++g) {
            if (g < 3) {
                #pragma unroll
                for (int i = 0; i < 8; ++i)
                    buf[(g + 1) & 1][i] = dub[(size_t)(p0 + inner * ((g + 1) * 8 + i)) * CC];
            }
            #pragma unroll
            for (int i = 0; i < 8; ++i) {
                int j = g * 8 + i;
                float2 dv = buf[g & 1][i];
                float dA[NN];
                #pragma unroll
                for (int nn = 0; nn < NN; ++nn) dA[nn] = __builtin_amdgcn_exp2f(A2[nn] * dv.x);
                float yv = 0.f;
                #pragma unroll
                for (int nn = 0; nn < NN; ++nn) {
                    float Bu = dv.y * sBm[j * 16 + nn];
                    h[nn] = fmaf(dA[nn], h[nn], Bu);
                    yv = fmaf(h[nn], sCm[j * 16 + nn], yv);
                }
                yD[((size_t)b * LL + p0 + inner * j) * CC + c] = 0.25f * yv;
            }
        }
    }
}

// ---------------- K6: sum 3 y-buffers + x*D, transpose to (B,C,L) -----------
__global__ __launch_bounds__(256) void k6_reduce(
    const float* __restrict__ feat, const float* __restrict__ D,
    const float* __restrict__ yA, const float* __restrict__ yB,
    const float* __restrict__ yC, float* __restrict__ out)
{
    int pt = blockIdx.x & 63;
    int ct = (blockIdx.x >> 6) & 3;
    int b  = blockIdx.x >> 8;
    int p0 = pt * 64, c0 = ct * 64;
    __shared__ float tile[64 * 65];
    {
        int cl = threadIdx.x & 63;
        int pg = threadIdx.x >> 6;
        #pragma unroll
        for (int pp = 0; pp < 16; ++pp) {
            int pl = pp * 4 + pg;
            size_t ix = ((size_t)b * LL + p0 + pl) * CC + c0 + cl;
            tile[cl * 65 + pl] = yA[ix] + yB[ix] + yC[ix];
        }
    }
    __syncthreads();
    {
        int pl = threadIdx.x & 63;
        int cg = threadIdx.x >> 6;
        #pragma unroll
        for (int cc = 0; cc < 16; ++cc) {
            int cloc = cc * 4 + cg;
            int c = c0 + cloc;
            size_t o = ((size_t)b * CC + c) * LL + p0 + pl;
            out[o] = tile[cloc * 65 + pl] + feat[o] * D[c];
        }
    }
}

extern "C" void kernel_launch(void* const* d_in, const int* in_sizes, int n_in,
                              void* d_out, int out_size, void* d_ws, size_t ws_size,
                              hipStream_t stream)
{
    const float* feat  = (const float*)d_in[0];
    const float* A_log = (const float*)d_in[1];
    const float* D     = (const float*)d_in[2];
    const float* Wd    = (const float*)d_in[3];
    const float* bd    = (const float*)d_in[4];
    const float* WB    = (const float*)d_in[5];
    const float* WC    = (const float*)d_in[6];
    float* out = (float*)d_out;

    float* ws  = (float*)d_ws;
    float* du  = ws;                                      //  4,194,304 (float2 pairs)
    float* Bm  = du  + (size_t)4194304;                   //    131,072
    float* Cm  = Bm  + (size_t)131072;                    //    131,072
    float* P   = Cm  + (size_t)131072;                    //  3,145,728 (3 cls)
    float* S   = P   + (size_t)3145728;                   //  3,145,728
    float* Hin = S   + (size_t)3145728;                   //  4,194,304 (4 dirs)
    float* yA  = Hin + (size_t)4194304;                   //  2,097,152
    float* yB  = yA  + (size_t)2097152;                   //  2,097,152
    float* yC  = yB  + (size_t)2097152;                   //  2,097,152

    k1_delta_gemm<<<1024, 256, 0, stream>>>(feat, Wd, bd, WB, WC, du, Bm, Cm);
    p1_aggr<<<768, 256, 0, stream>>>((const float2*)du, Bm, A_log, P, S);
    p2_scan<<<256, 128, 0, stream>>>(P, S, Hin);
    p3_replay<<<768, 256, 0, stream>>>((const float2*)du, Bm, Cm, A_log, Hin, yA, yB, yC);
    k6_reduce<<<512, 256, 0, stream>>>(feat, D, yA, yB, yC, out);
}

// Round 8
// 161.218 us; speedup vs baseline: 1.3864x; 1.0722x over previous
//
#include <hip/hip_runtime.h>
#include <cstdint>
#include <cstddef>

#define BB 2
#define CC 256
#define NN 16
#define LL 4096
#define NCH 128
#define CLEN 32
#define LCH 8           // l-chunk per k1 block
#define LOG2E 1.4426950408889634f

__device__ __forceinline__ float softplus_f(float z) {
    return fmaxf(z, 0.f) + log1pf(expf(-fabsf(z)));
}

__device__ __forceinline__ uint32_t pack_bf2(float d, float u) {
    uint32_t lo = (__float_as_uint(d) + 0x8000u) >> 16;
    uint32_t hh = (__float_as_uint(u) + 0x8000u) & 0xffff0000u;
    return hh | lo;
}

// ---------------- K1: delta/u + Bm/Cm, k-split-by-wave ----------------------
// block = (b, l-chunk of 8), 256 threads. Wave kq owns k in [64kq, 64kq+64):
// Wd read as float4 (16B/lane), feat row via wave-uniform s_load. Partials
// reduced across waves via LDS (one barrier). du stored as packed bf16x2.
__global__ __launch_bounds__(256) void k1_delta_gemm(
    const float* __restrict__ feat, const float* __restrict__ Wd,
    const float* __restrict__ bd, const float* __restrict__ WB,
    const float* __restrict__ WC, uint32_t* __restrict__ du,
    float* __restrict__ Bm, float* __restrict__ Cm)
{
    int lc = blockIdx.x & 511;          // 512 l-chunks of 8
    int b  = blockIdx.x >> 9;
    int l0 = lc * LCH;
    const float* fbase = feat + (size_t)b * CC * LL;

    int c4   = threadIdx.x & 63;                                   // c quad
    int kq   = __builtin_amdgcn_readfirstlane(threadIdx.x >> 6);   // wave id
    int hi   = (threadIdx.x >> 5) & 1;
    int slot = threadIdx.x & 31;
    int mat  = slot >> 4;               // 0=Bm 1=Cm
    int n    = slot & 15;
    const float* wBC = mat ? WC : WB;

    float accM[8][4] = {};              // [l][c-quad j], partial over 64 k's
    float accB[4] = {};                 // BC partial: l = 2j + hi

    int kbase = kq * 64;
    #pragma unroll 4
    for (int kk = 0; kk < 64; ++kk) {
        int k = kbase + kk;
        const float* frow = fbase + (size_t)k * LL + l0;   // wave-uniform
        float4 x0 = *(const float4*)(frow);
        float4 x1 = *(const float4*)(frow + 4);
        float4 wv = *(const float4*)&Wd[(size_t)k * CC + (c4 << 2)];
        float wb  = wBC[k * NN + n];
        float xs[8] = {x0.x, x0.y, x0.z, x0.w, x1.x, x1.y, x1.z, x1.w};
        #pragma unroll
        for (int l = 0; l < 8; ++l) {
            accM[l][0] = fmaf(xs[l], wv.x, accM[l][0]);
            accM[l][1] = fmaf(xs[l], wv.y, accM[l][1]);
            accM[l][2] = fmaf(xs[l], wv.z, accM[l][2]);
            accM[l][3] = fmaf(xs[l], wv.w, accM[l][3]);
        }
        accB[0] = fmaf(hi ? x0.y : x0.x, wb, accB[0]);
        accB[1] = fmaf(hi ? x0.w : x0.z, wb, accB[1]);
        accB[2] = fmaf(hi ? x1.y : x1.x, wb, accB[2]);
        accB[3] = fmaf(hi ? x1.w : x1.z, wb, accB[3]);
    }

    __shared__ float red[4 * 8 * 64 * 4];    // [kq][l][c4][4] = 32 KB
    __shared__ float redBC[4 * 2 * 32 * 4];  // [kq][hi][slot][j] = 4 KB
    #pragma unroll
    for (int l = 0; l < 8; ++l)
        *(float4*)&red[((kq * 8 + l) * 64 + c4) * 4] =
            make_float4(accM[l][0], accM[l][1], accM[l][2], accM[l][3]);
    *(float4*)&redBC[((kq * 2 + hi) * 32 + slot) * 4] =
        make_float4(accB[0], accB[1], accB[2], accB[3]);
    __syncthreads();

    // BC final: thread -> (lr = t>>5, slotr = t&31); partial at [q][lr&1][slotr][lr>>1]
    {
        int lr = threadIdx.x >> 5, slotr = threadIdx.x & 31;
        int jj = lr >> 1, hh = lr & 1;
        float s = 0.f;
        #pragma unroll
        for (int q = 0; q < 4; ++q)
            s += redBC[((q * 2 + hh) * 32 + slotr) * 4 + jj];
        int mr = slotr >> 4, nr = slotr & 15;
        (mr ? Cm : Bm)[((size_t)b * LL + l0 + lr) * NN + nr] = s;
    }

    // main final + epilogue: thread (c4, kq) handles l = 2kq, 2kq+1; c = 4*c4..+3
    float4 bd4 = *(const float4*)&bd[c4 << 2];
    float2 vx[4];
    #pragma unroll
    for (int j = 0; j < 4; ++j)
        vx[j] = *(const float2*)&fbase[(size_t)(c4 * 4 + j) * LL + l0 + kq * 2];
    #pragma unroll
    for (int lo = 0; lo < 2; ++lo) {
        int l = kq * 2 + lo;
        float z0 = 0.f, z1 = 0.f, z2 = 0.f, z3 = 0.f;
        #pragma unroll
        for (int q = 0; q < 4; ++q) {
            float4 p = *(float4*)&red[((q * 8 + l) * 64 + c4) * 4];
            z0 += p.x; z1 += p.y; z2 += p.z; z3 += p.w;
        }
        float d0 = softplus_f(z0 + bd4.x);
        float d1 = softplus_f(z1 + bd4.y);
        float d2 = softplus_f(z2 + bd4.z);
        float d3 = softplus_f(z3 + bd4.w);
        float x0v = lo ? vx[0].y : vx[0].x;
        float x1v = lo ? vx[1].y : vx[1].x;
        float x2v = lo ? vx[2].y : vx[2].x;
        float x3v = lo ? vx[3].y : vx[3].x;
        uint4 o;
        o.x = pack_bf2(d0, d0 * x0v);
        o.y = pack_bf2(d1, d1 * x1v);
        o.z = pack_bf2(d2, d2 * x2v);
        o.w = pack_bf2(d3, d3 * x3v);
        *(uint4*)&du[((size_t)b * LL + l0 + l) * CC + (c4 << 2)] = o;
    }
}

// ---------------- P1: per-chunk aggregates, 2-deep x 8-wide du prefetch -----
__global__ __launch_bounds__(256) void p1_aggr(
    const uint32_t* __restrict__ du, const float* __restrict__ Bm,
    const float* __restrict__ A_log, float* __restrict__ P, float* __restrict__ S)
{
    int blk = blockIdx.x;
    int cls = blk >> 8;
    int b   = (blk >> 7) & 1;
    int ch  = blk & 127;
    int p0, inner;
    if (cls == 0)      { p0 = 32 * ch;        inner = 1; }
    else if (cls == 1) { p0 = 4095 - 32 * ch; inner = -1; }
    else               { p0 = 63 - (ch >> 1) + 2048 * (ch & 1); inner = 64; }
    int c = threadIdx.x;
    __shared__ float sBm[CLEN * NN];
    for (int i = threadIdx.x; i < CLEN * NN; i += 256) {
        int j = i >> 4, nn = i & 15;
        sBm[i] = Bm[((size_t)b * LL + (p0 + inner * j)) * NN + nn];
    }
    float A2[NN];
    {
        const float4* al = (const float4*)(A_log + c * NN);
        #pragma unroll
        for (int q = 0; q < 4; ++q) {
            float4 v = al[q];
            A2[q*4+0] = -expf(v.x) * LOG2E;
            A2[q*4+1] = -expf(v.y) * LOG2E;
            A2[q*4+2] = -expf(v.z) * LOG2E;
            A2[q*4+3] = -expf(v.w) * LOG2E;
        }
    }
    __syncthreads();
    const uint32_t* dub = du + (size_t)b * LL * CC + c;
    uint32_t buf[2][8];
    #pragma unroll
    for (int i = 0; i < 8; ++i)
        buf[0][i] = dub[(size_t)(p0 + inner * i) * CC];
    float Sv[NN] = {};
    float sumd = 0.f;
    #pragma unroll
    for (int g = 0; g < 4; ++g) {
        if (g < 3) {
            #pragma unroll
            for (int i = 0; i < 8; ++i)
                buf[(g + 1) & 1][i] = dub[(size_t)(p0 + inner * ((g + 1) * 8 + i)) * CC];
        }
        #pragma unroll
        for (int i = 0; i < 8; ++i) {
            int j = g * 8 + i;
            uint32_t w = buf[g & 1][i];
            float dx = __uint_as_float(w << 16);
            float uy = __uint_as_float(w & 0xffff0000u);
            sumd += dx;
            float dA[NN];
            #pragma unroll
            for (int nn = 0; nn < NN; ++nn) dA[nn] = __builtin_amdgcn_exp2f(A2[nn] * dx);
            #pragma unroll
            for (int nn = 0; nn < NN; ++nn)
                Sv[nn] = fmaf(dA[nn], Sv[nn], uy * sBm[j * 16 + nn]);
        }
    }
    size_t base = ((size_t)((cls * 2 + b) * 128 + ch)) * 4096 + (size_t)c * 16;
    #pragma unroll
    for (int nn = 0; nn < NN; ++nn) {
        P[base + nn] = __builtin_amdgcn_exp2f(A2[nn] * sumd);
        S[base + nn] = Sv[nn];
    }
}

// ---------------- P2: scan chunk aggregates per direction -> Hin ------------
__global__ __launch_bounds__(128) void p2_scan(
    const float* __restrict__ P, const float* __restrict__ S, float* __restrict__ Hin)
{
    int r = blockIdx.x * 128 + threadIdx.x;   // 32768 rows
    int cn = r & 4095;
    int db = r >> 12;
    int d = db >> 1;
    int cls = (d == 1) ? 1 : ((d == 3) ? 2 : 0);
    int b = db & 1;
    const size_t cbase = ((size_t)(cls * 2 + b) * 128) * 4096 + cn;
    const size_t obase = ((size_t)db * 128) * 4096 + cn;
    float h = 0.f;
    for (int g = 0; g < 16; ++g) {
        float pv[8], sv[8];
        #pragma unroll
        for (int i = 0; i < 8; ++i) {
            int ch = g * 8 + i;
            int chm = (d == 2) ? (126 - 2 * (ch >> 1) + (ch & 1)) : ch;
            size_t ix = cbase + (size_t)chm * 4096;
            pv[i] = P[ix];
            sv[i] = S[ix];
        }
        #pragma unroll
        for (int i = 0; i < 8; ++i) {
            Hin[obase + (size_t)(g * 8 + i) * 4096] = h;
            h = fmaf(pv[i], h, sv[i]);
        }
    }
}

// ---------------- P3: replay + 2-deep x 8-wide du prefetch ------------------
__global__ __launch_bounds__(256) void p3_replay(
    const uint32_t* __restrict__ du, const float* __restrict__ Bm,
    const float* __restrict__ Cm, const float* __restrict__ A_log,
    const float* __restrict__ Hin, float* __restrict__ yA,
    float* __restrict__ yB, float* __restrict__ yC)
{
    int blk = blockIdx.x;
    int sec = blk >> 8;
    int b   = (blk >> 7) & 1;
    int ch  = blk & 127;
    int p0, inner;
    if (sec == 0)      { p0 = 32 * ch;        inner = 1; }
    else if (sec == 1) { p0 = 4095 - 32 * ch; inner = -1; }
    else               { p0 = 63 - (ch >> 1) + 2048 * (ch & 1); inner = 64; }
    int c = threadIdx.x;
    __shared__ float sBm[CLEN * NN];
    __shared__ float sCm[CLEN * NN];
    for (int i = threadIdx.x; i < CLEN * NN; i += 256) {
        int j = i >> 4, nn = i & 15;
        size_t o = ((size_t)b * LL + (p0 + inner * j)) * NN + nn;
        sBm[i] = Bm[o];
        sCm[i] = Cm[o];
    }
    float A2[NN];
    {
        const float4* al = (const float4*)(A_log + c * NN);
        #pragma unroll
        for (int q = 0; q < 4; ++q) {
            float4 v = al[q];
            A2[q*4+0] = -expf(v.x) * LOG2E;
            A2[q*4+1] = -expf(v.y) * LOG2E;
            A2[q*4+2] = -expf(v.z) * LOG2E;
            A2[q*4+3] = -expf(v.w) * LOG2E;
        }
    }
    const uint32_t* dub = du + (size_t)b * LL * CC + c;

    if (sec == 0) {
        int ch2 = 126 - (ch & ~1) + (ch & 1);
        float h0[NN], h2[NN];
        {
            const float4* hp0 = (const float4*)(Hin + ((size_t)(0 * 2 + b) * 128 + ch)  * 4096 + (size_t)c * 16);
            const float4* hp2 = (const float4*)(Hin + ((size_t)(2 * 2 + b) * 128 + ch2) * 4096 + (size_t)c * 16);
            #pragma unroll
            for (int q = 0; q < 4; ++q) {
                float4 v0 = hp0[q], v2 = hp2[q];
                h0[q*4+0]=v0.x; h0[q*4+1]=v0.y; h0[q*4+2]=v0.z; h0[q*4+3]=v0.w;
                h2[q*4+0]=v2.x; h2[q*4+1]=v2.y; h2[q*4+2]=v2.z; h2[q*4+3]=v2.w;
            }
        }
        __syncthreads();
        uint32_t buf[2][8];
        #pragma unroll
        for (int i = 0; i < 8; ++i)
            buf[0][i] = dub[(size_t)(p0 + i) * CC];
        #pragma unroll
        for (int g = 0; g < 4; ++g) {
            if (g < 3) {
                #pragma unroll
                for (int i = 0; i < 8; ++i)
                    buf[(g + 1) & 1][i] = dub[(size_t)(p0 + (g + 1) * 8 + i) * CC];
            }
            #pragma unroll
            for (int i = 0; i < 8; ++i) {
                int j = g * 8 + i;
                uint32_t w = buf[g & 1][i];
                float dx = __uint_as_float(w << 16);
                float uy = __uint_as_float(w & 0xffff0000u);
                float dA[NN];
                #pragma unroll
                for (int nn = 0; nn < NN; ++nn) dA[nn] = __builtin_amdgcn_exp2f(A2[nn] * dx);
                float y0v = 0.f, y2v = 0.f;
                #pragma unroll
                for (int nn = 0; nn < NN; ++nn) {
                    float Bu = uy * sBm[j * 16 + nn];
                    float cm = sCm[j * 16 + nn];
                    h0[nn] = fmaf(dA[nn], h0[nn], Bu);
                    h2[nn] = fmaf(dA[nn], h2[nn], Bu);
                    y0v = fmaf(h0[nn], cm, y0v);
                    y2v = fmaf(h2[nn], cm, y2v);
                }
                yA[((size_t)b * LL + p0 + j) * CC + c] = 0.25f * (y0v + y2v);
            }
        }
    } else {
        int d = (sec == 1) ? 1 : 3;
        float h[NN];
        {
            const float4* hp = (const float4*)(Hin + ((size_t)(d * 2 + b) * 128 + ch) * 4096 + (size_t)c * 16);
            #pragma unroll
            for (int q = 0; q < 4; ++q) {
                float4 v = hp[q];
                h[q*4+0]=v.x; h[q*4+1]=v.y; h[q*4+2]=v.z; h[q*4+3]=v.w;
            }
        }
        __syncthreads();
        float* yD = (sec == 1) ? yB : yC;
        uint32_t buf[2][8];
        #pragma unroll
        for (int i = 0; i < 8; ++i)
            buf[0][i] = dub[(size_t)(p0 + inner * i) * CC];
        #pragma unroll
        for (int g = 0; g < 4; ++g) {
            if (g < 3) {
                #pragma unroll
                for (int i = 0; i < 8; ++i)
                    buf[(g + 1) & 1][i] = dub[(size_t)(p0 + inner * ((g + 1) * 8 + i)) * CC];
            }
            #pragma unroll
            for (int i = 0; i < 8; ++i) {
                int j = g * 8 + i;
                uint32_t w = buf[g & 1][i];
                float dx = __uint_as_float(w << 16);
                float uy = __uint_as_float(w & 0xffff0000u);
                float dA[NN];
                #pragma unroll
                for (int nn = 0; nn < NN; ++nn) dA[nn] = __builtin_amdgcn_exp2f(A2[nn] * dx);
                float yv = 0.f;
                #pragma unroll
                for (int nn = 0; nn < NN; ++nn) {
                    float Bu = uy * sBm[j * 16 + nn];
                    h[nn] = fmaf(dA[nn], h[nn], Bu);
                    yv = fmaf(h[nn], sCm[j * 16 + nn], yv);
                }
                yD[((size_t)b * LL + p0 + inner * j) * CC + c] = 0.25f * yv;
            }
        }
    }
}

// ---------------- K6: sum 3 y-buffers + x*D, transpose to (B,C,L) -----------
__global__ __launch_bounds__(256) void k6_reduce(
    const float* __restrict__ feat, const float* __restrict__ D,
    const float* __restrict__ yA, const float* __restrict__ yB,
    const float* __restrict__ yC, float* __restrict__ out)
{
    int pt = blockIdx.x & 63;
    int ct = (blockIdx.x >> 6) & 3;
    int b  = blockIdx.x >> 8;
    int p0 = pt * 64, c0 = ct * 64;
    __shared__ float tile[64 * 65];
    {
        int cl = threadIdx.x & 63;
        int pg = threadIdx.x >> 6;
        #pragma unroll
        for (int pp = 0; pp < 16; ++pp) {
            int pl = pp * 4 + pg;
            size_t ix = ((size_t)b * LL + p0 + pl) * CC + c0 + cl;
            tile[cl * 65 + pl] = yA[ix] + yB[ix] + yC[ix];
        }
    }
    __syncthreads();
    {
        int pl = threadIdx.x & 63;
        int cg = threadIdx.x >> 6;
        #pragma unroll
        for (int cc = 0; cc < 16; ++cc) {
            int cloc = cc * 4 + cg;
            int c = c0 + cloc;
            size_t o = ((size_t)b * CC + c) * LL + p0 + pl;
            out[o] = tile[cloc * 65 + pl] + feat[o] * D[c];
        }
    }
}

extern "C" void kernel_launch(void* const* d_in, const int* in_sizes, int n_in,
                              void* d_out, int out_size, void* d_ws, size_t ws_size,
                              hipStream_t stream)
{
    const float* feat  = (const float*)d_in[0];
    const float* A_log = (const float*)d_in[1];
    const float* D     = (const float*)d_in[2];
    const float* Wd    = (const float*)d_in[3];
    const float* bd    = (const float*)d_in[4];
    const float* WB    = (const float*)d_in[5];
    const float* WC    = (const float*)d_in[6];
    float* out = (float*)d_out;

    float* ws  = (float*)d_ws;
    uint32_t* du = (uint32_t*)ws;                         //  2,097,152 u32 (bf16x2)
    float* Bm  = ws  + (size_t)2097152;                   //    131,072
    float* Cm  = Bm  + (size_t)131072;                    //    131,072
    float* P   = Cm  + (size_t)131072;                    //  3,145,728 (3 cls)
    float* S   = P   + (size_t)3145728;                   //  3,145,728
    float* Hin = S   + (size_t)3145728;                   //  4,194,304 (4 dirs)
    float* yA  = Hin + (size_t)4194304;                   //  2,097,152
    float* yB  = yA  + (size_t)2097152;                   //  2,097,152
    float* yC  = yB  + (size_t)2097152;                   //  2,097,152

    k1_delta_gemm<<<1024, 256, 0, stream>>>(feat, Wd, bd, WB, WC, du, Bm, Cm);
    p1_aggr<<<768, 256, 0, stream>>>(du, Bm, A_log, P, S);
    p2_scan<<<256, 128, 0, stream>>>(P, S, Hin);
    p3_replay<<<768, 256, 0, stream>>>(du, Bm, Cm, A_log, Hin, yA, yB, yC);
    k6_reduce<<<512, 256, 0, stream>>>(feat, D, yA, yB, yC, out);
}